// Round 1
// baseline (1716.349 us; speedup 1.0000x reference)
//
#include <hip/hip_runtime.h>
#include <math.h>

#define D_IN 128
#define D_OUT 64
#define BM 64
#define BNT 256   // 4 * 64 output columns (q,k,v,skip)
#define KB 32
#define SCALE_PARAM 2.0f

// ---------------- stats zero ----------------
__global__ void zero_stats_kernel(float* stats) {
    if (threadIdx.x < 8) stats[threadIdx.x] = 0.0f;
}

// ---------------- fused qkv+skip GEMM ----------------
// C[M=100000, 256] = x[M,128] @ [Wq|Wk|Wv|Wskip][128,256] + biases
// tile: 64 rows x 256 cols, 256 threads, 8x8 per thread
__global__ __launch_bounds__(256) void fused_gemm_kernel(
    const float* __restrict__ x,
    const float* __restrict__ Wq, const float* __restrict__ bq,
    const float* __restrict__ Wk, const float* __restrict__ bk,
    const float* __restrict__ Wv, const float* __restrict__ bv,
    const float* __restrict__ Ws, const float* __restrict__ bs,
    float* __restrict__ q, float* __restrict__ kk, float* __restrict__ v,
    float* __restrict__ skip, int N)
{
    __shared__ float xs[KB][BM + 4];   // transposed x tile, padded (stride 68 floats, 16B aligned)
    __shared__ float wsh[KB][BNT];     // W tile

    const int t = threadIdx.x;
    const int row0 = blockIdx.x * BM;
    const int tx = t & 31;     // col group (8 cols each)
    const int ty = t >> 5;     // row group (8 rows each)

    float acc[8][8];
#pragma unroll
    for (int i = 0; i < 8; ++i)
#pragma unroll
        for (int j = 0; j < 8; ++j) acc[i][j] = 0.f;

    const int m = t >> 6;          // matrix id for W loading column t
    const int c = t & 63;          // col within that matrix
    const float* Wm = (m == 0) ? Wq : (m == 1) ? Wk : (m == 2) ? Wv : Ws;

    for (int k0 = 0; k0 < D_IN; k0 += KB) {
        // W tile: rows k0..k0+31, this thread owns concat-col t
#pragma unroll
        for (int r = 0; r < KB; ++r)
            wsh[r][t] = Wm[(k0 + r) * D_OUT + c];
        // x tile, stored transposed: xs[k][row]
        {
            int r = t >> 2;            // 0..63
            int c4b = t & 3;           // base float4 col
#pragma unroll
            for (int it = 0; it < 2; ++it) {
                int cc = c4b + it * 4; // 0..7 float4 cols
                int grow = row0 + r;
                float4 xv = make_float4(0.f, 0.f, 0.f, 0.f);
                if (grow < N)
                    xv = *reinterpret_cast<const float4*>(&x[(size_t)grow * D_IN + k0 + cc * 4]);
                xs[cc * 4 + 0][r] = xv.x;
                xs[cc * 4 + 1][r] = xv.y;
                xs[cc * 4 + 2][r] = xv.z;
                xs[cc * 4 + 3][r] = xv.w;
            }
        }
        __syncthreads();
#pragma unroll
        for (int kq = 0; kq < KB; ++kq) {
            float a[8], b[8];
            float4 a0 = *reinterpret_cast<const float4*>(&xs[kq][ty * 8]);
            float4 a1 = *reinterpret_cast<const float4*>(&xs[kq][ty * 8 + 4]);
            float4 b0 = *reinterpret_cast<const float4*>(&wsh[kq][tx * 8]);
            float4 b1 = *reinterpret_cast<const float4*>(&wsh[kq][tx * 8 + 4]);
            a[0] = a0.x; a[1] = a0.y; a[2] = a0.z; a[3] = a0.w;
            a[4] = a1.x; a[5] = a1.y; a[6] = a1.z; a[7] = a1.w;
            b[0] = b0.x; b[1] = b0.y; b[2] = b0.z; b[3] = b0.w;
            b[4] = b1.x; b[5] = b1.y; b[6] = b1.z; b[7] = b1.w;
#pragma unroll
            for (int i = 0; i < 8; ++i)
#pragma unroll
                for (int j = 0; j < 8; ++j)
                    acc[i][j] = fmaf(a[i], b[j], acc[i][j]);
        }
        __syncthreads();
    }

    // epilogue: this thread's 8 cols live in one matrix (8 | 64)
    const int mo = (tx * 8) >> 6;
    const int co = (tx * 8) & 63;
    const float* bp = (mo == 0) ? bq : (mo == 1) ? bk : (mo == 2) ? bv : bs;
    float* op = (mo == 0) ? q : (mo == 1) ? kk : (mo == 2) ? v : skip;
#pragma unroll
    for (int i = 0; i < 8; ++i) {
        int grow = row0 + ty * 8 + i;
        if (grow >= N) continue;
        float o[8];
#pragma unroll
        for (int j = 0; j < 8; ++j) o[j] = acc[i][j] + bp[co + j];
        *reinterpret_cast<float4*>(&op[(size_t)grow * D_OUT + co])     = make_float4(o[0], o[1], o[2], o[3]);
        *reinterpret_cast<float4*>(&op[(size_t)grow * D_OUT + co + 4]) = make_float4(o[4], o[5], o[6], o[7]);
    }
}

// ---------------- per-edge attention logits + global stats ----------------
// 16 lanes per edge, float4 per lane over 64 channels
__global__ __launch_bounds__(256) void edge_alpha_kernel(
    const float* __restrict__ q, const float* __restrict__ k,
    const int* __restrict__ src, const int* __restrict__ dst,
    float* __restrict__ alpha, float* __restrict__ stats, int E)
{
    const int t = threadIdx.x;
    const int lane16 = t & 15;
    const int group = t >> 4;          // 16 groups per block
    float lsum = 0.f, lsq = 0.f;

    for (long long e = (long long)blockIdx.x * 16 + group; e < E;
         e += (long long)gridDim.x * 16) {
        int s = src[e];
        int d = dst[e];
        float4 qv = *reinterpret_cast<const float4*>(&q[(size_t)d * D_OUT + lane16 * 4]);
        float4 kv = *reinterpret_cast<const float4*>(&k[(size_t)s * D_OUT + lane16 * 4]);
        float p = qv.x * kv.x + qv.y * kv.y + qv.z * kv.z + qv.w * kv.w;
        p += __shfl_xor(p, 1, 64);
        p += __shfl_xor(p, 2, 64);
        p += __shfl_xor(p, 4, 64);
        p += __shfl_xor(p, 8, 64);
        float a = p * 0.125f;          // 1/sqrt(64)
        if (lane16 == 0) {
            alpha[e] = a;
            lsum += a;
            lsq += a * a;
        }
    }

    // block reduce (non-leaders hold 0)
#pragma unroll
    for (int off = 1; off < 64; off <<= 1) {
        lsum += __shfl_xor(lsum, off, 64);
        lsq  += __shfl_xor(lsq,  off, 64);
    }
    __shared__ float red[2][4];
    const int wid = t >> 6;
    if ((t & 63) == 0) { red[0][wid] = lsum; red[1][wid] = lsq; }
    __syncthreads();
    if (t == 0) {
        float s  = red[0][0] + red[0][1] + red[0][2] + red[0][3];
        float s2 = red[1][0] + red[1][1] + red[1][2] + red[1][3];
        atomicAdd(&stats[0], s);
        atomicAdd(&stats[1], s2);
    }
}

// ---------------- finalize mean/std ----------------
__global__ void finalize_stats_kernel(float* stats, int E) {
    if (threadIdx.x == 0) {
        float s = stats[0], s2 = stats[1];
        float mean = s / (float)E;
        float var = (s2 - (float)E * mean * mean) / (float)(E - 1);
        stats[2] = mean;
        stats[3] = SCALE_PARAM / sqrtf(var);   // alpha*S/std
    }
}

// ---------------- sigmoid + scatter-add ----------------
__global__ __launch_bounds__(256) void scatter_kernel(
    const float* __restrict__ v, const int* __restrict__ src,
    const int* __restrict__ dst, const float* __restrict__ alpha,
    const float* __restrict__ stats, float* __restrict__ out, int E)
{
    const int t = threadIdx.x;
    const int lane16 = t & 15;
    const int group = t >> 4;
    const float mean = stats[2];
    const float coef = stats[3];

    for (long long e = (long long)blockIdx.x * 16 + group; e < E;
         e += (long long)gridDim.x * 16) {
        int s = src[e];
        int d = dst[e];
        float a = (alpha[e] - mean) * coef;
        a = 1.0f / (1.0f + __expf(-a));
        float4 vv = *reinterpret_cast<const float4*>(&v[(size_t)s * D_OUT + lane16 * 4]);
        float* op = &out[(size_t)d * D_OUT + lane16 * 4];
        atomicAdd(op + 0, vv.x * a);
        atomicAdd(op + 1, vv.y * a);
        atomicAdd(op + 2, vv.z * a);
        atomicAdd(op + 3, vv.w * a);
    }
}

extern "C" void kernel_launch(void* const* d_in, const int* in_sizes, int n_in,
                              void* d_out, int out_size, void* d_ws, size_t ws_size,
                              hipStream_t stream) {
    const float* x     = (const float*)d_in[0];
    const int*   eidx  = (const int*)d_in[1];
    const float* Wq    = (const float*)d_in[2];
    const float* bq    = (const float*)d_in[3];
    const float* Wk    = (const float*)d_in[4];
    const float* bk    = (const float*)d_in[5];
    const float* Wv    = (const float*)d_in[6];
    const float* bv    = (const float*)d_in[7];
    const float* Ws    = (const float*)d_in[8];
    const float* bs    = (const float*)d_in[9];
    float* out = (float*)d_out;

    const int N = in_sizes[0] / D_IN;
    const int E = in_sizes[1] / 2;
    const int* src = eidx;          // edge_index[0]
    const int* dst = eidx + E;      // edge_index[1]

    char* base = (char*)d_ws;
    const size_t nodef = (size_t)N * D_OUT * sizeof(float);
    float* q     = (float*)(base);
    float* k     = (float*)(base + nodef);
    float* v     = (float*)(base + 2 * nodef);
    float* alpha = (float*)(base + 3 * nodef);
    size_t ofs_stats = 3 * nodef + (size_t)E * sizeof(float);
    ofs_stats = (ofs_stats + 255) & ~(size_t)255;
    float* stats = (float*)(base + ofs_stats);

    zero_stats_kernel<<<1, 64, 0, stream>>>(stats);

    const int gemm_grid = (N + BM - 1) / BM;
    fused_gemm_kernel<<<gemm_grid, 256, 0, stream>>>(
        x, Wq, bq, Wk, bk, Wv, bv, Ws, bs, q, k, v, out, N);

    const int egrid = 8192;
    edge_alpha_kernel<<<egrid, 256, 0, stream>>>(q, k, src, dst, alpha, stats, E);
    finalize_stats_kernel<<<1, 64, 0, stream>>>(stats, E);
    scatter_kernel<<<egrid, 256, 0, stream>>>(v, src, dst, alpha, stats, out, E);
}

// Round 2
// 591.403 us; speedup vs baseline: 2.9022x; 2.9022x over previous
//
#include <hip/hip_runtime.h>
#include <math.h>

#define D_IN 128
#define D_OUT 64
#define BM 64
#define BNT 256   // 4 * 64 output columns (q,k,v,skip)
#define KB 32
#define SCALE_PARAM 2.0f

// ---------------- fused qkv+skip GEMM ----------------
// C[M=100000, 256] = x[M,128] @ [Wq|Wk|Wv|Wskip][128,256] + biases
__global__ __launch_bounds__(256) void fused_gemm_kernel(
    const float* __restrict__ x,
    const float* __restrict__ Wq, const float* __restrict__ bq,
    const float* __restrict__ Wk, const float* __restrict__ bk,
    const float* __restrict__ Wv, const float* __restrict__ bv,
    const float* __restrict__ Ws, const float* __restrict__ bs,
    float* __restrict__ q, float* __restrict__ kk, float* __restrict__ v,
    float* __restrict__ skip, int N)
{
    __shared__ float xs[KB][BM + 4];
    __shared__ float wsh[KB][BNT];

    const int t = threadIdx.x;
    const int row0 = blockIdx.x * BM;
    const int tx = t & 31;
    const int ty = t >> 5;

    float acc[8][8];
#pragma unroll
    for (int i = 0; i < 8; ++i)
#pragma unroll
        for (int j = 0; j < 8; ++j) acc[i][j] = 0.f;

    const int m = t >> 6;
    const int c = t & 63;
    const float* Wm = (m == 0) ? Wq : (m == 1) ? Wk : (m == 2) ? Wv : Ws;

    for (int k0 = 0; k0 < D_IN; k0 += KB) {
#pragma unroll
        for (int r = 0; r < KB; ++r)
            wsh[r][t] = Wm[(k0 + r) * D_OUT + c];
        {
            int r = t >> 2;
            int c4b = t & 3;
#pragma unroll
            for (int it = 0; it < 2; ++it) {
                int cc = c4b + it * 4;
                int grow = row0 + r;
                float4 xv = make_float4(0.f, 0.f, 0.f, 0.f);
                if (grow < N)
                    xv = *reinterpret_cast<const float4*>(&x[(size_t)grow * D_IN + k0 + cc * 4]);
                xs[cc * 4 + 0][r] = xv.x;
                xs[cc * 4 + 1][r] = xv.y;
                xs[cc * 4 + 2][r] = xv.z;
                xs[cc * 4 + 3][r] = xv.w;
            }
        }
        __syncthreads();
#pragma unroll
        for (int kq = 0; kq < KB; ++kq) {
            float a[8], b[8];
            float4 a0 = *reinterpret_cast<const float4*>(&xs[kq][ty * 8]);
            float4 a1 = *reinterpret_cast<const float4*>(&xs[kq][ty * 8 + 4]);
            float4 b0 = *reinterpret_cast<const float4*>(&wsh[kq][tx * 8]);
            float4 b1 = *reinterpret_cast<const float4*>(&wsh[kq][tx * 8 + 4]);
            a[0] = a0.x; a[1] = a0.y; a[2] = a0.z; a[3] = a0.w;
            a[4] = a1.x; a[5] = a1.y; a[6] = a1.z; a[7] = a1.w;
            b[0] = b0.x; b[1] = b0.y; b[2] = b0.z; b[3] = b0.w;
            b[4] = b1.x; b[5] = b1.y; b[6] = b1.z; b[7] = b1.w;
#pragma unroll
            for (int i = 0; i < 8; ++i)
#pragma unroll
                for (int j = 0; j < 8; ++j)
                    acc[i][j] = fmaf(a[i], b[j], acc[i][j]);
        }
        __syncthreads();
    }

    const int mo = (tx * 8) >> 6;
    const int co = (tx * 8) & 63;
    const float* bp = (mo == 0) ? bq : (mo == 1) ? bk : (mo == 2) ? bv : bs;
    float* op = (mo == 0) ? q : (mo == 1) ? kk : (mo == 2) ? v : skip;
#pragma unroll
    for (int i = 0; i < 8; ++i) {
        int grow = row0 + ty * 8 + i;
        if (grow >= N) continue;
        float o[8];
#pragma unroll
        for (int j = 0; j < 8; ++j) o[j] = acc[i][j] + bp[co + j];
        *reinterpret_cast<float4*>(&op[(size_t)grow * D_OUT + co])     = make_float4(o[0], o[1], o[2], o[3]);
        *reinterpret_cast<float4*>(&op[(size_t)grow * D_OUT + co + 4]) = make_float4(o[4], o[5], o[6], o[7]);
    }
}

// ---------------- per-edge logits + stats + dst histogram ----------------
__global__ __launch_bounds__(256) void edge_alpha_kernel(
    const float* __restrict__ q, const float* __restrict__ k,
    const int* __restrict__ src, const int* __restrict__ dst,
    float* __restrict__ alpha, float* __restrict__ stats,
    int* __restrict__ cnt, int E)
{
    const int t = threadIdx.x;
    const int lane16 = t & 15;
    const int group = t >> 4;
    float lsum = 0.f, lsq = 0.f;

    for (long long e = (long long)blockIdx.x * 16 + group; e < E;
         e += (long long)gridDim.x * 16) {
        int s = src[e];
        int d = dst[e];
        float4 qv = *reinterpret_cast<const float4*>(&q[(size_t)d * D_OUT + lane16 * 4]);
        float4 kv = *reinterpret_cast<const float4*>(&k[(size_t)s * D_OUT + lane16 * 4]);
        float p = qv.x * kv.x + qv.y * kv.y + qv.z * kv.z + qv.w * kv.w;
        p += __shfl_xor(p, 1, 64);
        p += __shfl_xor(p, 2, 64);
        p += __shfl_xor(p, 4, 64);
        p += __shfl_xor(p, 8, 64);
        float a = p * 0.125f;          // 1/sqrt(64)
        if (lane16 == 0) {
            alpha[e] = a;
            lsum += a;
            lsq += a * a;
            atomicAdd(&cnt[d], 1);
        }
    }

#pragma unroll
    for (int off = 1; off < 64; off <<= 1) {
        lsum += __shfl_xor(lsum, off, 64);
        lsq  += __shfl_xor(lsq,  off, 64);
    }
    __shared__ float red[2][4];
    const int wid = t >> 6;
    if ((t & 63) == 0) { red[0][wid] = lsum; red[1][wid] = lsq; }
    __syncthreads();
    if (t == 0) {
        float s  = red[0][0] + red[0][1] + red[0][2] + red[0][3];
        float s2 = red[1][0] + red[1][1] + red[1][2] + red[1][3];
        atomicAdd(&stats[0], s);
        atomicAdd(&stats[1], s2);
    }
}

// ---------------- finalize mean/std ----------------
__global__ void finalize_stats_kernel(float* stats, int E) {
    if (threadIdx.x == 0) {
        float s = stats[0], s2 = stats[1];
        float mean = s / (float)E;
        float var = (s2 - (float)E * mean * mean) / (float)(E - 1);
        stats[2] = mean;
        stats[3] = SCALE_PARAM / sqrtf(var);
    }
}

// ---------------- scan: phase 1 (per-block exclusive scan of cnt) -------
__global__ __launch_bounds__(256) void scan1_kernel(
    const int* __restrict__ cnt, int* __restrict__ row_start,
    int* __restrict__ bsum, int N)
{
    const int t = threadIdx.x;
    const int base = blockIdx.x * 1024 + t * 4;
    int v0 = 0, v1 = 0, v2 = 0, v3 = 0;
    if (base + 3 < N) {
        int4 c = *reinterpret_cast<const int4*>(&cnt[base]);
        v0 = c.x; v1 = c.y; v2 = c.z; v3 = c.w;
    } else {
        if (base < N)     v0 = cnt[base];
        if (base + 1 < N) v1 = cnt[base + 1];
        if (base + 2 < N) v2 = cnt[base + 2];
    }
    const int tsum = v0 + v1 + v2 + v3;
    int x = tsum;
    const int lane = t & 63;
#pragma unroll
    for (int off = 1; off < 64; off <<= 1) {
        int n = __shfl_up(x, off, 64);
        if (lane >= off) x += n;
    }
    __shared__ int wsum[4];
    const int wid = t >> 6;
    if (lane == 63) wsum[wid] = x;
    __syncthreads();
    int wofs = 0;
    for (int w = 0; w < wid; ++w) wofs += wsum[w];
    const int incl = x + wofs;
    const int excl = incl - tsum;
    if (base < N)     row_start[base]     = excl;
    if (base + 1 < N) row_start[base + 1] = excl + v0;
    if (base + 2 < N) row_start[base + 2] = excl + v0 + v1;
    if (base + 3 < N) row_start[base + 3] = excl + v0 + v1 + v2;
    if (t == 255) bsum[blockIdx.x] = incl;
}

// ---------------- scan: phase 2 (scan of block sums, tiny) -------------
__global__ void scan2_kernel(int* bsum, int NB, int* row_start_N) {
    if (threadIdx.x == 0) {
        int run = 0;
        for (int i = 0; i < NB; ++i) {
            int tv = bsum[i];
            bsum[i] = run;
            run += tv;
        }
        *row_start_N = run;   // row_start[N] = E
    }
}

// ---------------- scan: phase 3 (add block offsets, copy to ofs) -------
__global__ __launch_bounds__(256) void scan3_kernel(
    int* __restrict__ row_start, int* __restrict__ ofs,
    const int* __restrict__ bsum, int N)
{
    const int base = blockIdx.x * 1024 + threadIdx.x * 4;
    const int add = bsum[blockIdx.x];
#pragma unroll
    for (int i = 0; i < 4; ++i) {
        if (base + i < N) {
            int vv = row_start[base + i] + add;
            row_start[base + i] = vv;
            ofs[base + i] = vv;
        }
    }
}

// ---------------- bucket scatter (sigmoid applied here) ----------------
__global__ __launch_bounds__(256) void scatter_sort_kernel(
    const int* __restrict__ src, const int* __restrict__ dst,
    const float* __restrict__ alpha, const float* __restrict__ stats,
    int* __restrict__ ofs, int* __restrict__ sorted_src,
    float* __restrict__ sorted_a, int E)
{
    const int e = blockIdx.x * 256 + threadIdx.x;
    if (e >= E) return;
    const float mean = stats[2];
    const float coef = stats[3];
    int d = dst[e];
    float a = (alpha[e] - mean) * coef;
    a = 1.0f / (1.0f + __expf(-a));
    int pos = atomicAdd(&ofs[d], 1);
    sorted_src[pos] = src[e];
    sorted_a[pos] = a;
}

// ---------------- gather: one wave per node, lane = channel ------------
__global__ __launch_bounds__(256) void gather_kernel(
    const float* __restrict__ v, const int* __restrict__ sorted_src,
    const float* __restrict__ sorted_a, const int* __restrict__ row_start,
    float* __restrict__ out, int N)
{
    const int node = blockIdx.x * 4 + (threadIdx.x >> 6);
    if (node >= N) return;
    const int lane = threadIdx.x & 63;
    const int s0 = row_start[node];
    const int s1 = row_start[node + 1];
    float acc0 = 0.f, acc1 = 0.f;
    int j = s0;
    for (; j + 1 < s1; j += 2) {
        int sA = sorted_src[j];
        int sB = sorted_src[j + 1];
        float aA = sorted_a[j];
        float aB = sorted_a[j + 1];
        acc0 = fmaf(v[(size_t)sA * D_OUT + lane], aA, acc0);
        acc1 = fmaf(v[(size_t)sB * D_OUT + lane], aB, acc1);
    }
    if (j < s1) {
        int sA = sorted_src[j];
        float aA = sorted_a[j];
        acc0 = fmaf(v[(size_t)sA * D_OUT + lane], aA, acc0);
    }
    out[(size_t)node * D_OUT + lane] += acc0 + acc1;
}

extern "C" void kernel_launch(void* const* d_in, const int* in_sizes, int n_in,
                              void* d_out, int out_size, void* d_ws, size_t ws_size,
                              hipStream_t stream) {
    const float* x     = (const float*)d_in[0];
    const int*   eidx  = (const int*)d_in[1];
    const float* Wq    = (const float*)d_in[2];
    const float* bq    = (const float*)d_in[3];
    const float* Wk    = (const float*)d_in[4];
    const float* bk    = (const float*)d_in[5];
    const float* Wv    = (const float*)d_in[6];
    const float* bv    = (const float*)d_in[7];
    const float* Ws    = (const float*)d_in[8];
    const float* bs    = (const float*)d_in[9];
    float* out = (float*)d_out;

    const int N = in_sizes[0] / D_IN;
    const int E = in_sizes[1] / 2;
    const int* src = eidx;
    const int* dst = eidx + E;

    // ---- workspace carve-up (256B aligned) ----
    char* base = (char*)d_ws;
    size_t cur = 0;
    auto carve = [&](size_t bytes) -> char* {
        char* p = base + cur;
        cur = (cur + bytes + 255) & ~(size_t)255;
        return p;
    };
    const size_t nodef = (size_t)N * D_OUT * sizeof(float);
    float* q          = (float*)carve(nodef);
    float* k          = (float*)carve(nodef);
    float* v          = (float*)carve(nodef);
    float* alpha      = (float*)carve((size_t)E * sizeof(float));
    int*   sorted_src = (int*)carve((size_t)E * sizeof(int));
    float* sorted_a   = (float*)carve((size_t)E * sizeof(float));
    // cnt + stats share one memset region
    char*  zreg       = carve((size_t)N * sizeof(int) + 256);
    int*   cnt        = (int*)zreg;
    float* stats      = (float*)(zreg + (((size_t)N * sizeof(int) + 255) & ~(size_t)255));
    int*   row_start  = (int*)carve((size_t)(N + 1) * sizeof(int));
    int*   ofs        = (int*)carve((size_t)N * sizeof(int));
    const int NB = (N + 1023) / 1024;
    int*   bsum       = (int*)carve((size_t)NB * sizeof(int));

    hipMemsetAsync(zreg, 0, (size_t)N * sizeof(int) + 256, stream);

    const int gemm_grid = (N + BM - 1) / BM;
    fused_gemm_kernel<<<gemm_grid, 256, 0, stream>>>(
        x, Wq, bq, Wk, bk, Wv, bv, Ws, bs, q, k, v, out, N);

    const int egrid = 8192;
    edge_alpha_kernel<<<egrid, 256, 0, stream>>>(q, k, src, dst, alpha, stats, cnt, E);

    scan1_kernel<<<NB, 256, 0, stream>>>(cnt, row_start, bsum, N);
    scan2_kernel<<<1, 64, 0, stream>>>(bsum, NB, &row_start[N]);
    scan3_kernel<<<NB, 256, 0, stream>>>(row_start, ofs, bsum, N);

    finalize_stats_kernel<<<1, 64, 0, stream>>>(stats, E);

    scatter_sort_kernel<<<(E + 255) / 256, 256, 0, stream>>>(
        src, dst, alpha, stats, ofs, sorted_src, sorted_a, E);

    gather_kernel<<<(N + 3) / 4, 256, 0, stream>>>(
        v, sorted_src, sorted_a, row_start, out, N);
}

// Round 3
// 570.487 us; speedup vs baseline: 3.0086x; 1.0367x over previous
//
#include <hip/hip_runtime.h>
#include <math.h>

#define D_IN 128
#define D_OUT 64
#define BM 64
#define BNT 256   // 4 * 64 output columns (q,k,v,skip)
#define KB 32
#define SCALE_PARAM 2.0f

typedef unsigned short ushortt;

__device__ __forceinline__ ushortt f2bf(float f) {
    union { float f; unsigned u; } cv; cv.f = f;
    unsigned u = cv.u;
    return (ushortt)((u + 0x7FFFu + ((u >> 16) & 1u)) >> 16);
}
__device__ __forceinline__ float bf2f(ushortt h) {
    union { unsigned u; float f; } cv; cv.u = ((unsigned)h) << 16;
    return cv.f;
}
__device__ __forceinline__ float bflo(unsigned w) {
    union { unsigned u; float f; } cv; cv.u = w << 16;
    return cv.f;
}
__device__ __forceinline__ float bfhi(unsigned w) {
    union { unsigned u; float f; } cv; cv.u = w & 0xFFFF0000u;
    return cv.f;
}

// ---------------- fused qkv+skip GEMM ----------------
// q,k,v written as bf16; skip written f32 directly into out
__global__ __launch_bounds__(256) void fused_gemm_kernel(
    const float* __restrict__ x,
    const float* __restrict__ Wq, const float* __restrict__ bq,
    const float* __restrict__ Wk, const float* __restrict__ bk,
    const float* __restrict__ Wv, const float* __restrict__ bv,
    const float* __restrict__ Ws, const float* __restrict__ bs,
    ushortt* __restrict__ q, ushortt* __restrict__ kk, ushortt* __restrict__ v,
    float* __restrict__ skip, int N)
{
    __shared__ float xs[KB][BM + 4];
    __shared__ float wsh[KB][BNT];

    const int t = threadIdx.x;
    const int row0 = blockIdx.x * BM;
    const int tx = t & 31;
    const int ty = t >> 5;

    float acc[8][8];
#pragma unroll
    for (int i = 0; i < 8; ++i)
#pragma unroll
        for (int j = 0; j < 8; ++j) acc[i][j] = 0.f;

    const int m = t >> 6;
    const int c = t & 63;
    const float* Wm = (m == 0) ? Wq : (m == 1) ? Wk : (m == 2) ? Wv : Ws;

    for (int k0 = 0; k0 < D_IN; k0 += KB) {
#pragma unroll
        for (int r = 0; r < KB; ++r)
            wsh[r][t] = Wm[(k0 + r) * D_OUT + c];
        {
            int r = t >> 2;
            int c4b = t & 3;
#pragma unroll
            for (int it = 0; it < 2; ++it) {
                int cc = c4b + it * 4;
                int grow = row0 + r;
                float4 xv = make_float4(0.f, 0.f, 0.f, 0.f);
                if (grow < N)
                    xv = *reinterpret_cast<const float4*>(&x[(size_t)grow * D_IN + k0 + cc * 4]);
                xs[cc * 4 + 0][r] = xv.x;
                xs[cc * 4 + 1][r] = xv.y;
                xs[cc * 4 + 2][r] = xv.z;
                xs[cc * 4 + 3][r] = xv.w;
            }
        }
        __syncthreads();
#pragma unroll
        for (int kq = 0; kq < KB; ++kq) {
            float a[8], b[8];
            float4 a0 = *reinterpret_cast<const float4*>(&xs[kq][ty * 8]);
            float4 a1 = *reinterpret_cast<const float4*>(&xs[kq][ty * 8 + 4]);
            float4 b0 = *reinterpret_cast<const float4*>(&wsh[kq][tx * 8]);
            float4 b1 = *reinterpret_cast<const float4*>(&wsh[kq][tx * 8 + 4]);
            a[0] = a0.x; a[1] = a0.y; a[2] = a0.z; a[3] = a0.w;
            a[4] = a1.x; a[5] = a1.y; a[6] = a1.z; a[7] = a1.w;
            b[0] = b0.x; b[1] = b0.y; b[2] = b0.z; b[3] = b0.w;
            b[4] = b1.x; b[5] = b1.y; b[6] = b1.z; b[7] = b1.w;
#pragma unroll
            for (int i = 0; i < 8; ++i)
#pragma unroll
                for (int j = 0; j < 8; ++j)
                    acc[i][j] = fmaf(a[i], b[j], acc[i][j]);
        }
        __syncthreads();
    }

    const int mo = (tx * 8) >> 6;
    const int co = (tx * 8) & 63;
    const float* bp = (mo == 0) ? bq : (mo == 1) ? bk : (mo == 2) ? bv : bs;
#pragma unroll
    for (int i = 0; i < 8; ++i) {
        int grow = row0 + ty * 8 + i;
        if (grow >= N) continue;
        float o[8];
#pragma unroll
        for (int j = 0; j < 8; ++j) o[j] = acc[i][j] + bp[co + j];
        if (mo == 3) {
            *reinterpret_cast<float4*>(&skip[(size_t)grow * D_OUT + co])     = make_float4(o[0], o[1], o[2], o[3]);
            *reinterpret_cast<float4*>(&skip[(size_t)grow * D_OUT + co + 4]) = make_float4(o[4], o[5], o[6], o[7]);
        } else {
            ushortt* op = (mo == 0) ? q : (mo == 1) ? kk : v;
            uint4 pk;
            pk.x = (unsigned)f2bf(o[0]) | ((unsigned)f2bf(o[1]) << 16);
            pk.y = (unsigned)f2bf(o[2]) | ((unsigned)f2bf(o[3]) << 16);
            pk.z = (unsigned)f2bf(o[4]) | ((unsigned)f2bf(o[5]) << 16);
            pk.w = (unsigned)f2bf(o[6]) | ((unsigned)f2bf(o[7]) << 16);
            *reinterpret_cast<uint4*>(&op[(size_t)grow * D_OUT + co]) = pk;
        }
    }
}

// ---------------- per-edge logits + stats + dst histogram ----------------
// 8 lanes per edge, one uint4 (8 bf16) per lane
__global__ __launch_bounds__(256) void edge_alpha_kernel(
    const ushortt* __restrict__ q, const ushortt* __restrict__ k,
    const int* __restrict__ src, const int* __restrict__ dst,
    float* __restrict__ alpha, float* __restrict__ stats,
    int* __restrict__ cnt, int E)
{
    const int t = threadIdx.x;
    const int lane8 = t & 7;
    const int group = t >> 3;          // 32 edge slots per block
    float lsum = 0.f, lsq = 0.f;

    for (long long e = (long long)blockIdx.x * 32 + group; e < E;
         e += (long long)gridDim.x * 32) {
        int s = src[e];
        int d = dst[e];
        uint4 qv = *reinterpret_cast<const uint4*>(&q[(size_t)d * D_OUT + lane8 * 8]);
        uint4 kv = *reinterpret_cast<const uint4*>(&k[(size_t)s * D_OUT + lane8 * 8]);
        float p = bflo(qv.x) * bflo(kv.x) + bfhi(qv.x) * bfhi(kv.x);
        p = fmaf(bflo(qv.y), bflo(kv.y), p); p = fmaf(bfhi(qv.y), bfhi(kv.y), p);
        p = fmaf(bflo(qv.z), bflo(kv.z), p); p = fmaf(bfhi(qv.z), bfhi(kv.z), p);
        p = fmaf(bflo(qv.w), bflo(kv.w), p); p = fmaf(bfhi(qv.w), bfhi(kv.w), p);
        p += __shfl_xor(p, 1, 64);
        p += __shfl_xor(p, 2, 64);
        p += __shfl_xor(p, 4, 64);
        float a = p * 0.125f;          // 1/sqrt(64)
        if (lane8 == 0) {
            alpha[e] = a;
            lsum += a;
            lsq += a * a;
            atomicAdd(&cnt[d], 1);
        }
    }

#pragma unroll
    for (int off = 1; off < 64; off <<= 1) {
        lsum += __shfl_xor(lsum, off, 64);
        lsq  += __shfl_xor(lsq,  off, 64);
    }
    __shared__ float red[2][4];
    const int wid = t >> 6;
    if ((t & 63) == 0) { red[0][wid] = lsum; red[1][wid] = lsq; }
    __syncthreads();
    if (t == 0) {
        float s  = red[0][0] + red[0][1] + red[0][2] + red[0][3];
        float s2 = red[1][0] + red[1][1] + red[1][2] + red[1][3];
        atomicAdd(&stats[0], s);
        atomicAdd(&stats[1], s2);
    }
}

// ---------------- finalize mean/std ----------------
__global__ void finalize_stats_kernel(float* stats, int E) {
    if (threadIdx.x == 0) {
        float s = stats[0], s2 = stats[1];
        float mean = s / (float)E;
        float var = (s2 - (float)E * mean * mean) / (float)(E - 1);
        stats[2] = mean;
        stats[3] = SCALE_PARAM / sqrtf(var);
    }
}

// ---------------- scan: phase 1 ----------------
__global__ __launch_bounds__(256) void scan1_kernel(
    const int* __restrict__ cnt, int* __restrict__ row_start,
    int* __restrict__ bsum, int N)
{
    const int t = threadIdx.x;
    const int base = blockIdx.x * 1024 + t * 4;
    int v0 = 0, v1 = 0, v2 = 0, v3 = 0;
    if (base + 3 < N) {
        int4 c = *reinterpret_cast<const int4*>(&cnt[base]);
        v0 = c.x; v1 = c.y; v2 = c.z; v3 = c.w;
    } else {
        if (base < N)     v0 = cnt[base];
        if (base + 1 < N) v1 = cnt[base + 1];
        if (base + 2 < N) v2 = cnt[base + 2];
    }
    const int tsum = v0 + v1 + v2 + v3;
    int x = tsum;
    const int lane = t & 63;
#pragma unroll
    for (int off = 1; off < 64; off <<= 1) {
        int n = __shfl_up(x, off, 64);
        if (lane >= off) x += n;
    }
    __shared__ int wsum[4];
    const int wid = t >> 6;
    if (lane == 63) wsum[wid] = x;
    __syncthreads();
    int wofs = 0;
    for (int w = 0; w < wid; ++w) wofs += wsum[w];
    const int incl = x + wofs;
    const int excl = incl - tsum;
    if (base < N)     row_start[base]     = excl;
    if (base + 1 < N) row_start[base + 1] = excl + v0;
    if (base + 2 < N) row_start[base + 2] = excl + v0 + v1;
    if (base + 3 < N) row_start[base + 3] = excl + v0 + v1 + v2;
    if (t == 255) bsum[blockIdx.x] = incl;
}

// ---------------- scan: phase 2 ----------------
__global__ void scan2_kernel(int* bsum, int NB, int* row_start_N) {
    if (threadIdx.x == 0) {
        int run = 0;
        for (int i = 0; i < NB; ++i) {
            int tv = bsum[i];
            bsum[i] = run;
            run += tv;
        }
        *row_start_N = run;
    }
}

// ---------------- scan: phase 3 ----------------
__global__ __launch_bounds__(256) void scan3_kernel(
    int* __restrict__ row_start, int* __restrict__ ofs,
    const int* __restrict__ bsum, int N)
{
    const int base = blockIdx.x * 1024 + threadIdx.x * 4;
    const int add = bsum[blockIdx.x];
#pragma unroll
    for (int i = 0; i < 4; ++i) {
        if (base + i < N) {
            int vv = row_start[base + i] + add;
            row_start[base + i] = vv;
            ofs[base + i] = vv;
        }
    }
}

// ---------------- bucket scatter (sigmoid applied here) ----------------
__global__ __launch_bounds__(256) void scatter_sort_kernel(
    const int* __restrict__ src, const int* __restrict__ dst,
    const float* __restrict__ alpha, const float* __restrict__ stats,
    int* __restrict__ ofs, int* __restrict__ sorted_src,
    float* __restrict__ sorted_a, int E)
{
    const int e = blockIdx.x * 256 + threadIdx.x;
    if (e >= E) return;
    const float mean = stats[2];
    const float coef = stats[3];
    int d = dst[e];
    float a = (alpha[e] - mean) * coef;
    a = 1.0f / (1.0f + __expf(-a));
    int pos = atomicAdd(&ofs[d], 1);
    sorted_src[pos] = src[e];
    sorted_a[pos] = a;
}

// ---------------- gather: one wave per node, lane = channel ------------
__global__ __launch_bounds__(256) void gather_kernel(
    const ushortt* __restrict__ v, const int* __restrict__ sorted_src,
    const float* __restrict__ sorted_a, const int* __restrict__ row_start,
    float* __restrict__ out, int N)
{
    const int node = blockIdx.x * 4 + (threadIdx.x >> 6);
    if (node >= N) return;
    const int lane = threadIdx.x & 63;
    const int s0 = row_start[node];
    const int s1 = row_start[node + 1];
    float acc0 = 0.f, acc1 = 0.f;
    int j = s0;
    for (; j + 1 < s1; j += 2) {
        int sA = sorted_src[j];
        int sB = sorted_src[j + 1];
        float aA = sorted_a[j];
        float aB = sorted_a[j + 1];
        acc0 = fmaf(bf2f(v[(size_t)sA * D_OUT + lane]), aA, acc0);
        acc1 = fmaf(bf2f(v[(size_t)sB * D_OUT + lane]), aB, acc1);
    }
    if (j < s1) {
        acc0 = fmaf(bf2f(v[(size_t)sorted_src[j] * D_OUT + lane]), sorted_a[j], acc0);
    }
    out[(size_t)node * D_OUT + lane] += acc0 + acc1;
}

extern "C" void kernel_launch(void* const* d_in, const int* in_sizes, int n_in,
                              void* d_out, int out_size, void* d_ws, size_t ws_size,
                              hipStream_t stream) {
    const float* x     = (const float*)d_in[0];
    const int*   eidx  = (const int*)d_in[1];
    const float* Wq    = (const float*)d_in[2];
    const float* bq    = (const float*)d_in[3];
    const float* Wk    = (const float*)d_in[4];
    const float* bk    = (const float*)d_in[5];
    const float* Wv    = (const float*)d_in[6];
    const float* bv    = (const float*)d_in[7];
    const float* Ws    = (const float*)d_in[8];
    const float* bs    = (const float*)d_in[9];
    float* out = (float*)d_out;

    const int N = in_sizes[0] / D_IN;
    const int E = in_sizes[1] / 2;
    const int* src = eidx;
    const int* dst = eidx + E;

    char* base = (char*)d_ws;
    size_t cur = 0;
    auto carve = [&](size_t bytes) -> char* {
        char* p = base + cur;
        cur = (cur + bytes + 255) & ~(size_t)255;
        return p;
    };
    const size_t nodebf = (size_t)N * D_OUT * sizeof(ushortt);
    ushortt* q        = (ushortt*)carve(nodebf);
    ushortt* k        = (ushortt*)carve(nodebf);
    ushortt* v        = (ushortt*)carve(nodebf);
    float* alpha      = (float*)carve((size_t)E * sizeof(float));
    int*   sorted_src = (int*)carve((size_t)E * sizeof(int));
    float* sorted_a   = (float*)carve((size_t)E * sizeof(float));
    char*  zreg       = carve((size_t)N * sizeof(int) + 256);
    int*   cnt        = (int*)zreg;
    float* stats      = (float*)(zreg + (((size_t)N * sizeof(int) + 255) & ~(size_t)255));
    int*   row_start  = (int*)carve((size_t)(N + 1) * sizeof(int));
    int*   ofs        = (int*)carve((size_t)N * sizeof(int));
    const int NB = (N + 1023) / 1024;
    int*   bsum       = (int*)carve((size_t)NB * sizeof(int));

    hipMemsetAsync(zreg, 0, (size_t)N * sizeof(int) + 256, stream);

    const int gemm_grid = (N + BM - 1) / BM;
    fused_gemm_kernel<<<gemm_grid, 256, 0, stream>>>(
        x, Wq, bq, Wk, bk, Wv, bv, Ws, bs, q, k, v, out, N);

    const int egrid = 8192;
    edge_alpha_kernel<<<egrid, 256, 0, stream>>>(q, k, src, dst, alpha, stats, cnt, E);

    scan1_kernel<<<NB, 256, 0, stream>>>(cnt, row_start, bsum, N);
    scan2_kernel<<<1, 64, 0, stream>>>(bsum, NB, &row_start[N]);
    scan3_kernel<<<NB, 256, 0, stream>>>(row_start, ofs, bsum, N);

    finalize_stats_kernel<<<1, 64, 0, stream>>>(stats, E);

    scatter_sort_kernel<<<(E + 255) / 256, 256, 0, stream>>>(
        src, dst, alpha, stats, ofs, sorted_src, sorted_a, E);

    gather_kernel<<<(N + 3) / 4, 256, 0, stream>>>(
        v, sorted_src, sorted_a, row_start, out, N);
}